// Round 8
// baseline (213.367 us; speedup 1.0000x reference)
//
#include <hip/hip_runtime.h>
#include <hip/hip_bf16.h>
#include <stdint.h>

typedef __attribute__((ext_vector_type(4))) float f32x4;
typedef __attribute__((ext_vector_type(16))) float f32x16;
typedef __attribute__((ext_vector_type(8))) short s16x8;
typedef __attribute__((ext_vector_type(4))) short s16x4;
typedef __attribute__((ext_vector_type(4))) unsigned int u32x4;

#define DEV static __device__ __forceinline__

constexpr int B_ = 4, H_ = 16, N_ = 2048;
constexpr float CL_ = 0.18033688011112042f;  // dh^-0.5 * log2(e), folded into q

DEV short f2bf(float x) {
  __hip_bfloat16 h = __float2bfloat16(x);
  return *reinterpret_cast<short*>(&h);
}

DEV uint32_t cvtpk(float lo, float hi) {  // packed bf16 (RNE), 1 instr
  uint32_t r;
  asm("v_cvt_pk_bf16_f32 %0, %1, %2" : "=v"(r) : "v"(lo), "v"(hi));
  return r;
}

DEV void gload16(const void* g, void* l) {
  __builtin_amdgcn_global_load_lds((const __attribute__((address_space(1))) void*)g,
                                   (__attribute__((address_space(3))) void*)l, 16, 0, 0);
}

// ---------------- prep: fp32 -> bf16 cast (x) ----------------
__global__ void k_cvt(const float* __restrict__ x, short* __restrict__ xb) {
  int i = (blockIdx.x * 256 + threadIdx.x) * 8;
  const float4* p = reinterpret_cast<const float4*>(x + i);
  float4 a = p[0], b = p[1];
  s16x8 o;
  o[0] = f2bf(a.x); o[1] = f2bf(a.y); o[2] = f2bf(a.z); o[3] = f2bf(a.w);
  o[4] = f2bf(b.x); o[5] = f2bf(b.y); o[6] = f2bf(b.z); o[7] = f2bf(b.w);
  *reinterpret_cast<s16x8*>(xb + i) = o;
}

// ------------- prep: W [R][C] fp32 -> WT [C][R] bf16 -------------
__global__ void k_tw(const float* __restrict__ W, short* __restrict__ WT, int R, int C) {
  __shared__ short t[64][72];
  int r0 = blockIdx.y * 64, c0 = blockIdx.x * 64;
  int tid = threadIdx.x;
  int r = tid >> 2, cp = (tid & 3) * 16;
  const float4* s4 = reinterpret_cast<const float4*>(W + (size_t)(r0 + r) * C + c0 + cp);
  float4 f0 = s4[0], f1 = s4[1], f2 = s4[2], f3 = s4[3];
  short* tr = &t[r][cp];
  tr[0] = f2bf(f0.x); tr[1] = f2bf(f0.y); tr[2]  = f2bf(f0.z); tr[3]  = f2bf(f0.w);
  tr[4] = f2bf(f1.x); tr[5] = f2bf(f1.y); tr[6]  = f2bf(f1.z); tr[7]  = f2bf(f1.w);
  tr[8] = f2bf(f2.x); tr[9] = f2bf(f2.y); tr[10] = f2bf(f2.z); tr[11] = f2bf(f2.w);
  tr[12] = f2bf(f3.x); tr[13] = f2bf(f3.y); tr[14] = f2bf(f3.z); tr[15] = f2bf(f3.w);
  __syncthreads();
  int cc = tid >> 2, rp = (tid & 3) * 16;
  short buf[16];
#pragma unroll
  for (int i = 0; i < 16; ++i) buf[i] = t[rp + i][cc];
  short* dst = WT + (size_t)(c0 + cc) * R + r0 + rp;
  *reinterpret_cast<s16x8*>(dst) = *reinterpret_cast<s16x8*>(buf);
  *reinterpret_cast<s16x8*>(dst + 8) = *reinterpret_cast<s16x8*>(buf + 8);
}

// ------------- transpose v [BH][N][64] -> vT [BH][64][N] -------------
__global__ void k_tv(const short* __restrict__ v, short* __restrict__ vT) {
  __shared__ short t[64][72];
  int bh = blockIdx.y, n0 = blockIdx.x * 64;
  int tid = threadIdx.x;
  int r = tid >> 2, cp = (tid & 3) * 16;
  const short* src = v + ((size_t)bh * N_ + n0 + r) * 64 + cp;
  *reinterpret_cast<s16x8*>(&t[r][cp]) = *reinterpret_cast<const s16x8*>(src);
  *reinterpret_cast<s16x8*>(&t[r][cp + 8]) = *reinterpret_cast<const s16x8*>(src + 8);
  __syncthreads();
  int d = tid >> 2, np = (tid & 3) * 16;
  short buf[16];
#pragma unroll
  for (int i = 0; i < 16; ++i) buf[i] = t[np + i][d];
  short* dst = vT + ((size_t)bh * 64 + d) * N_ + n0 + np;
  *reinterpret_cast<s16x8*>(dst) = *reinterpret_cast<s16x8*>(buf);
  *reinterpret_cast<s16x8*>(dst + 8) = *reinterpret_cast<s16x8*>(buf + 8);
}

// ------------- GEMM: A[M][K] bf16 x BT[N][K] bf16 (m97 structure + XCD swizzle) ------
template <int EPI>
__global__ __launch_bounds__(256, 2)
void k_gemm(const short* __restrict__ A, const short* __restrict__ BT,
            int M, int N, int K,
            short* __restrict__ oq, short* __restrict__ ok, short* __restrict__ ov,
            const float* __restrict__ bias, float* __restrict__ out) {
  __shared__ short As[128 * 32];
  __shared__ short Bs[128 * 32];
  const int tid = threadIdx.x;
  // bijective XCD swizzle (gridDim.x == 64, nwg % 8 == 0): XCD x gets contiguous tiles
  const int id = blockIdx.y * 64 + blockIdx.x;
  const int cpx = (64 * gridDim.y) >> 3;
  const int sw = (id & 7) * cpx + (id >> 3);
  const int m0 = (sw & 63) * 128, n0 = (sw >> 6) * 128;
  const int lane = tid & 63, w = tid >> 6, g = lane >> 4, c = lane & 15;
  const int wr = w >> 1, wc = w & 1;
  f32x4 acc[4][4] = {};
  const int trow = tid >> 2, tk = (tid & 3) * 8;
  const short* ga = A + (size_t)(m0 + trow) * K + tk;
  const short* gb = BT + (size_t)(n0 + trow) * K + tk;
  short* la = As + tid * 8;
  short* lb = Bs + tid * 8;
  for (int k0 = 0; k0 < K; k0 += 32) {
    gload16(ga + k0, la);
    gload16(ga + (size_t)64 * K + k0, la + 2048);
    gload16(gb + k0, lb);
    gload16(gb + (size_t)64 * K + k0, lb + 2048);
    __syncthreads();
    s16x8 af[4], bf[4];
#pragma unroll
    for (int i = 0; i < 4; ++i)
      af[i] = *reinterpret_cast<const s16x8*>(As + (wr * 64 + i * 16 + c) * 32 + g * 8);
#pragma unroll
    for (int j = 0; j < 4; ++j)
      bf[j] = *reinterpret_cast<const s16x8*>(Bs + (wc * 64 + j * 16 + c) * 32 + g * 8);
#pragma unroll
    for (int i = 0; i < 4; ++i)
#pragma unroll
      for (int j = 0; j < 4; ++j)
        acc[i][j] = __builtin_amdgcn_mfma_f32_16x16x32_bf16(af[i], bf[j], acc[i][j], 0, 0, 0);
    __syncthreads();
  }
  if (EPI == 0) {
#pragma unroll
    for (int bj = 0; bj < 4; ++bj) {
      int ncol = n0 + wc * 64 + bj * 16 + c;
      int part = ncol >> 10;
      int c10 = ncol & 1023;
      int h = c10 >> 6, d = c10 & 63;
      short* dst0 = part == 0 ? oq : (part == 1 ? ok : ov);
      float qs = (part == 0) ? CL_ : 1.0f;
#pragma unroll
      for (int ai = 0; ai < 4; ++ai) {
#pragma unroll
        for (int r = 0; r < 4; ++r) {
          int mrow = m0 + wr * 64 + ai * 16 + g * 4 + r;
          int b = mrow >> 11, nr = mrow & 2047;
          dst0[((size_t)((b * H_ + h) * N_ + nr) << 6) + d] = f2bf(acc[ai][bj][r] * qs);
        }
      }
    }
  } else {
#pragma unroll
    for (int bj = 0; bj < 4; ++bj) {
      int ncol = n0 + wc * 64 + bj * 16 + c;
      float bb = bias[ncol];
#pragma unroll
      for (int ai = 0; ai < 4; ++ai) {
#pragma unroll
        for (int r = 0; r < 4; ++r) {
          int mrow = m0 + wr * 64 + ai * 16 + g * 4 + r;
          out[(size_t)mrow * N + ncol] = acc[ai][bj][r] + bb;
        }
      }
    }
  }
}

// ------------- flash attention: 32x32 MFMA, QBLK=32/wave, 4 blocks/CU -------------
// R8: conflict-free LDS swizzle slot = col ^ ((row ^ row>>3) & 7) (spreads the
// stride-8 lane groups that 4-way-conflicted in R7), lp split into 4 accumulators.
// Swapped QK^T (S^T = mfma(K,Q)); P in registers via cvt_pk + permlane32_swap;
// streaming no-max softmax (q pre-scaled by CL_).
__global__ __launch_bounds__(256, 4)
void k_attn(const short* __restrict__ q, const short* __restrict__ kk,
            const short* __restrict__ vT, short* __restrict__ ao) {
  __shared__ __align__(16) char smem[32768];  // 2 slots x (K 8K + V 8K)
  constexpr int NT = N_ / 64;  // 32 kv tiles
  int bh = blockIdx.x, qb = blockIdx.y;  // bh fast => same-head blocks on one XCD
  int b = bh >> 4, head = bh & 15;
  int tid = threadIdx.x, w = tid >> 6, lane = tid & 63;
  int half = lane >> 5, qc = lane & 31;
  const size_t ho = (size_t)bh * (N_ * 64);
  const short* Q = q + ho;
  const char* Kc = reinterpret_cast<const char*>(kk + ho);
  const char* Vc = reinterpret_cast<const char*>(vT + ho);
  int q0w = qb * 128 + w * 32;
  // Q B-fragments [ks: k 16-slice]: lane holds q=qc, d=ks*16+half*8+e
  s16x8 qf[4];
#pragma unroll
  for (int ks = 0; ks < 4; ++ks)
    qf[ks] = *reinterpret_cast<const s16x8*>(Q + (size_t)(q0w + qc) * 64 + ks * 16 + half * 8);
  f32x16 ot[2] = {};  // O^T accum [d 32-block]
  float lp0 = 0.f, lp1 = 0.f, lp2 = 0.f, lp3 = 0.f;  // parallel exp-sum chains
  // read-side swizzle: rows r and r+32 differ by ^0x40 in slot bits
  const int rsw0 = ((qc ^ (qc >> 3)) & 7) << 4;  // for rows 0..31 (row = qc)
  const int rsw1 = rsw0 ^ 0x40;                  // for rows 32..63 (row = 32+qc)
  // staging geometry: 1024 16B chunks per 16KB slot; this thread's 4 chunks.
  // LDS dest is linear (tid*16); global source col-slot = (tid&7) ^ swz8(row).
  const int s_i0 = tid, s_i1 = tid + 256;
  const int s_r0 = s_i0 >> 3, s_r1 = s_i1 >> 3;
  const int s_c0 = (((s_i0 & 7) ^ ((s_r0 ^ (s_r0 >> 3)) & 7)) << 4);
  const int s_c1 = (((s_i1 & 7) ^ ((s_r1 ^ (s_r1 >> 3)) & 7)) << 4);
#define STAGE(T)                                                                       \
  {                                                                                    \
    char* nb = smem + ((T) & 1) * 16384;                                               \
    gload16(Kc + (size_t)((T) * 64 + s_r0) * 128 + s_c0, nb + s_i0 * 16);              \
    gload16(Kc + (size_t)((T) * 64 + s_r1) * 128 + s_c1, nb + s_i1 * 16);              \
    gload16(Vc + (size_t)s_r0 * 4096 + (T) * 128 + s_c0, nb + 8192 + s_i0 * 16);       \
    gload16(Vc + (size_t)s_r1 * 4096 + (T) * 128 + s_c1, nb + 8192 + s_i1 * 16);       \
  }
  STAGE(0);
  __syncthreads();
  for (int tt = 0; tt < NT; ++tt) {
    if (tt + 1 < NT) STAGE(tt + 1);
    const char* kb_ = smem + (tt & 1) * 16384;
    const char* vb_ = kb_ + 8192;
    f32x16 st[2];  // S^T [j kv-blk]
#pragma unroll
    for (int j = 0; j < 2; ++j) {
      const int rs = j ? rsw1 : rsw0;
      s16x8 kfj[4];
#pragma unroll
      for (int ks = 0; ks < 4; ++ks)
        kfj[ks] = *reinterpret_cast<const s16x8*>(kb_ + (j * 32 + qc) * 128 + ((ks * 32 + half * 16) ^ rs));
      f32x16 acc = {};
      __builtin_amdgcn_s_setprio(1);
#pragma unroll
      for (int ks = 0; ks < 4; ++ks)
        acc = __builtin_amdgcn_mfma_f32_32x32x16_bf16(kfj[ks], qf[ks], acc, 0, 0, 0);
      __builtin_amdgcn_s_setprio(0);
      st[j] = acc;
    }
    // streaming softmax (scores pre-scaled by CL_): exp2, 4 parallel partial sums
#pragma unroll
    for (int j = 0; j < 2; ++j)
#pragma unroll
      for (int r = 0; r < 16; ++r) {
        float p = __builtin_amdgcn_exp2f(st[j][r]);
        st[j][r] = p;
        if ((r & 3) == 0) lp0 += p;
        else if ((r & 3) == 1) lp1 += p;
        else if ((r & 3) == 2) lp2 += p;
        else lp3 += p;
      }
    // P -> PV B-fragments in registers: per (j,bb): 4 cvtpk + 2 permlane32_swap
    u32x4 pwv[4];
#pragma unroll
    for (int j = 0; j < 2; ++j)
#pragma unroll
      for (int bb = 0; bb < 2; ++bb)
#pragma unroll
        for (int p = 0; p < 2; ++p) {
          uint32_t Aw = cvtpk(st[j][8 * bb + 2 * p], st[j][8 * bb + 2 * p + 1]);
          uint32_t Bw = cvtpk(st[j][8 * bb + 4 + 2 * p], st[j][8 * bb + 4 + 2 * p + 1]);
          asm volatile("v_permlane32_swap_b32 %0, %1" : "+v"(Aw), "+v"(Bw));
          pwv[j * 2 + bb][p] = Aw;       // word m = p
          pwv[j * 2 + bb][p + 2] = Bw;   // word m = p + 2
        }
    // V^T A-fragments [db: d 32-block][kb4: kv 16-block]: lane holds d=db*32+qc
#pragma unroll
    for (int db = 0; db < 2; ++db) {
      const int rs = db ? rsw1 : rsw0;
      s16x8 vf[4];
#pragma unroll
      for (int kb4 = 0; kb4 < 4; ++kb4)
        vf[kb4] = *reinterpret_cast<const s16x8*>(vb_ + (db * 32 + qc) * 128 + ((kb4 * 32 + half * 16) ^ rs));
      f32x16 acc = ot[db];
      __builtin_amdgcn_s_setprio(1);
#pragma unroll
      for (int kb4 = 0; kb4 < 4; ++kb4)
        acc = __builtin_amdgcn_mfma_f32_32x32x16_bf16(
            vf[kb4], __builtin_bit_cast(s16x8, pwv[kb4]), acc, 0, 0, 0);
      __builtin_amdgcn_s_setprio(0);
      ot[db] = acc;
    }
    __syncthreads();
  }
#undef STAGE
  // l: this lane's half + partner half
  float lp = (lp0 + lp1) + (lp2 + lp3);
  float linv = 1.f / (lp + __shfl_xor(lp, 32, 64));
  // epilogue: per-wave LDS region (all slot reads sealed by final barrier)
  short* Oq = reinterpret_cast<short*>(smem) + w * 2304;  // [32][72]
#pragma unroll
  for (int db = 0; db < 2; ++db)
#pragma unroll
    for (int m = 0; m < 4; ++m) {
      uint2 pk;
      pk.x = cvtpk(ot[db][4 * m] * linv, ot[db][4 * m + 1] * linv);
      pk.y = cvtpk(ot[db][4 * m + 2] * linv, ot[db][4 * m + 3] * linv);
      *reinterpret_cast<uint2*>(Oq + qc * 72 + db * 32 + m * 8 + half * 4) = pk;
    }
  int q2 = lane >> 1, dcol = (lane & 1) * 32;
  size_t ro = (size_t)(b * N_ + q0w + q2) * 1024 + head * 64 + dcol;
#pragma unroll
  for (int ch = 0; ch < 4; ++ch) {
    s16x8 vv = *reinterpret_cast<const s16x8*>(Oq + q2 * 72 + dcol + ch * 8);
    *reinterpret_cast<s16x8*>(ao + ro + ch * 8) = vv;
  }
}

extern "C" void kernel_launch(void* const* d_in, const int* in_sizes, int n_in,
                              void* d_out, int out_size, void* d_ws, size_t ws_size,
                              hipStream_t stream) {
  const float* x = (const float*)d_in[0];
  const float* w_qkv = (const float*)d_in[1];
  const float* w_out = (const float*)d_in[2];
  const float* b_out = (const float*)d_in[3];
  float* out = (float*)d_out;
  char* ws = (char*)d_ws;
  short* xb    = (short*)(ws);                // [8192][1024] bf16 (reused as ao later)
  short* wqkvT = (short*)(ws + 16777216);     // [3072][1024]
  short* woutT = (short*)(ws + 23068672);     // [1024][1024]
  short* qB    = (short*)(ws + 25165824);     // [B][H][N][64] (pre-scaled by CL_)
  short* kB    = (short*)(ws + 41943040);
  short* vtmp  = (short*)(ws + 58720256);
  short* vTT   = (short*)(ws + 75497472);     // [B][H][64][N]
  short* ao    = xb;                          // alias: xb dead after gemm<0>

  k_cvt<<<4096, 256, 0, stream>>>(x, xb);
  k_tw<<<dim3(48, 16), 256, 0, stream>>>(w_qkv, wqkvT, 1024, 3072);
  k_tw<<<dim3(16, 16), 256, 0, stream>>>(w_out, woutT, 1024, 1024);
  k_gemm<0><<<dim3(64, 24), 256, 0, stream>>>(xb, wqkvT, 8192, 3072, 1024,
                                              qB, kB, vtmp, nullptr, nullptr);
  k_tv<<<dim3(32, 64), 256, 0, stream>>>(vtmp, vTT);
  k_attn<<<dim3(64, 16), 256, 0, stream>>>(qB, kB, vTT, ao);
  k_gemm<1><<<dim3(64, 8), 256, 0, stream>>>(ao, woutT, 8192, 1024, 1024,
                                             nullptr, nullptr, nullptr, b_out, out);
}

// Round 9
// 196.760 us; speedup vs baseline: 1.0844x; 1.0844x over previous
//
#include <hip/hip_runtime.h>
#include <hip/hip_bf16.h>
#include <stdint.h>

typedef __attribute__((ext_vector_type(4))) float f32x4;
typedef __attribute__((ext_vector_type(16))) float f32x16;
typedef __attribute__((ext_vector_type(8))) short s16x8;
typedef __attribute__((ext_vector_type(4))) short s16x4;
typedef __attribute__((ext_vector_type(4))) unsigned int u32x4;

#define DEV static __device__ __forceinline__

constexpr int B_ = 4, H_ = 16, N_ = 2048;
constexpr float CL_ = 0.18033688011112042f;  // dh^-0.5 * log2(e), folded into q

DEV short f2bf(float x) {
  __hip_bfloat16 h = __float2bfloat16(x);
  return *reinterpret_cast<short*>(&h);
}

DEV uint32_t cvtpk(float lo, float hi) {  // packed bf16 (RNE), 1 instr
  uint32_t r;
  asm("v_cvt_pk_bf16_f32 %0, %1, %2" : "=v"(r) : "v"(lo), "v"(hi));
  return r;
}

DEV void gload16(const void* g, void* l) {
  __builtin_amdgcn_global_load_lds((const __attribute__((address_space(1))) void*)g,
                                   (__attribute__((address_space(3))) void*)l, 16, 0, 0);
}

// ---------------- fused prep: x cast + both weight transposes (one launch) ----------
// blocks [0,4096): cvt x -> bf16; [4096,4864): wqkv transpose; [4864,5120): wout.
__global__ void k_prep(const float* __restrict__ x, short* __restrict__ xb,
                       const float* __restrict__ wqkv, short* __restrict__ wqkvT,
                       const float* __restrict__ wout, short* __restrict__ woutT) {
  __shared__ short t[64][72];
  int bid = blockIdx.x, tid = threadIdx.x;
  if (bid < 4096) {
    int i = (bid * 256 + tid) * 8;
    const float4* p = reinterpret_cast<const float4*>(x + i);
    float4 a = p[0], b = p[1];
    s16x8 o;
    o[0] = f2bf(a.x); o[1] = f2bf(a.y); o[2] = f2bf(a.z); o[3] = f2bf(a.w);
    o[4] = f2bf(b.x); o[5] = f2bf(b.y); o[6] = f2bf(b.z); o[7] = f2bf(b.w);
    *reinterpret_cast<s16x8*>(xb + i) = o;
    return;
  }
  const float* W;
  short* WT;
  int R = 1024, C, r0, c0;
  if (bid < 4864) {
    int id = bid - 4096;
    W = wqkv; WT = wqkvT; C = 3072;
    c0 = (id % 48) * 64; r0 = (id / 48) * 64;
  } else {
    int id = bid - 4864;
    W = wout; WT = woutT; C = 1024;
    c0 = (id % 16) * 64; r0 = (id / 16) * 64;
  }
  int r = tid >> 2, cp = (tid & 3) * 16;
  const float4* s4 = reinterpret_cast<const float4*>(W + (size_t)(r0 + r) * C + c0 + cp);
  float4 f0 = s4[0], f1 = s4[1], f2 = s4[2], f3 = s4[3];
  short* tr = &t[r][cp];
  tr[0] = f2bf(f0.x); tr[1] = f2bf(f0.y); tr[2]  = f2bf(f0.z); tr[3]  = f2bf(f0.w);
  tr[4] = f2bf(f1.x); tr[5] = f2bf(f1.y); tr[6]  = f2bf(f1.z); tr[7]  = f2bf(f1.w);
  tr[8] = f2bf(f2.x); tr[9] = f2bf(f2.y); tr[10] = f2bf(f2.z); tr[11] = f2bf(f2.w);
  tr[12] = f2bf(f3.x); tr[13] = f2bf(f3.y); tr[14] = f2bf(f3.z); tr[15] = f2bf(f3.w);
  __syncthreads();
  int cc = tid >> 2, rp = (tid & 3) * 16;
  short buf[16];
#pragma unroll
  for (int i = 0; i < 16; ++i) buf[i] = t[rp + i][cc];
  short* dst = WT + (size_t)(c0 + cc) * R + r0 + rp;
  *reinterpret_cast<s16x8*>(dst) = *reinterpret_cast<s16x8*>(buf);
  *reinterpret_cast<s16x8*>(dst + 8) = *reinterpret_cast<s16x8*>(buf + 8);
}

// ------------- transpose v [BH][N][64] -> vT [BH][64][N] -------------
__global__ void k_tv(const short* __restrict__ v, short* __restrict__ vT) {
  __shared__ short t[64][72];
  int bh = blockIdx.y, n0 = blockIdx.x * 64;
  int tid = threadIdx.x;
  int r = tid >> 2, cp = (tid & 3) * 16;
  const short* src = v + ((size_t)bh * N_ + n0 + r) * 64 + cp;
  *reinterpret_cast<s16x8*>(&t[r][cp]) = *reinterpret_cast<const s16x8*>(src);
  *reinterpret_cast<s16x8*>(&t[r][cp + 8]) = *reinterpret_cast<const s16x8*>(src + 8);
  __syncthreads();
  int d = tid >> 2, np = (tid & 3) * 16;
  short buf[16];
#pragma unroll
  for (int i = 0; i < 16; ++i) buf[i] = t[np + i][d];
  short* dst = vT + ((size_t)bh * 64 + d) * N_ + n0 + np;
  *reinterpret_cast<s16x8*>(dst) = *reinterpret_cast<s16x8*>(buf);
  *reinterpret_cast<s16x8*>(dst + 8) = *reinterpret_cast<s16x8*>(buf + 8);
}

// ------------- GEMM: A[M][K] bf16 x BT[N][K] bf16 (m97 structure) -------------
template <int EPI>
__global__ __launch_bounds__(256, 2)
void k_gemm(const short* __restrict__ A, const short* __restrict__ BT,
            int M, int N, int K,
            short* __restrict__ oq, short* __restrict__ ok, short* __restrict__ ov,
            const float* __restrict__ bias, float* __restrict__ out) {
  __shared__ short As[128 * 32];
  __shared__ short Bs[128 * 32];
  const int tid = threadIdx.x;
  const int m0 = blockIdx.x * 128, n0 = blockIdx.y * 128;
  const int lane = tid & 63, w = tid >> 6, g = lane >> 4, c = lane & 15;
  const int wr = w >> 1, wc = w & 1;
  f32x4 acc[4][4] = {};
  const int trow = tid >> 2, tk = (tid & 3) * 8;
  const short* ga = A + (size_t)(m0 + trow) * K + tk;
  const short* gb = BT + (size_t)(n0 + trow) * K + tk;
  short* la = As + tid * 8;
  short* lb = Bs + tid * 8;
  for (int k0 = 0; k0 < K; k0 += 32) {
    gload16(ga + k0, la);
    gload16(ga + (size_t)64 * K + k0, la + 2048);
    gload16(gb + k0, lb);
    gload16(gb + (size_t)64 * K + k0, lb + 2048);
    __syncthreads();
    s16x8 af[4], bf[4];
#pragma unroll
    for (int i = 0; i < 4; ++i)
      af[i] = *reinterpret_cast<const s16x8*>(As + (wr * 64 + i * 16 + c) * 32 + g * 8);
#pragma unroll
    for (int j = 0; j < 4; ++j)
      bf[j] = *reinterpret_cast<const s16x8*>(Bs + (wc * 64 + j * 16 + c) * 32 + g * 8);
#pragma unroll
    for (int i = 0; i < 4; ++i)
#pragma unroll
      for (int j = 0; j < 4; ++j)
        acc[i][j] = __builtin_amdgcn_mfma_f32_16x16x32_bf16(af[i], bf[j], acc[i][j], 0, 0, 0);
    __syncthreads();
  }
  if (EPI == 0) {
#pragma unroll
    for (int bj = 0; bj < 4; ++bj) {
      int ncol = n0 + wc * 64 + bj * 16 + c;
      int part = ncol >> 10;
      int c10 = ncol & 1023;
      int h = c10 >> 6, d = c10 & 63;
      short* dst0 = part == 0 ? oq : (part == 1 ? ok : ov);
      float qs = (part == 0) ? CL_ : 1.0f;
#pragma unroll
      for (int ai = 0; ai < 4; ++ai) {
#pragma unroll
        for (int r = 0; r < 4; ++r) {
          int mrow = m0 + wr * 64 + ai * 16 + g * 4 + r;
          int b = mrow >> 11, nr = mrow & 2047;
          dst0[((size_t)((b * H_ + h) * N_ + nr) << 6) + d] = f2bf(acc[ai][bj][r] * qs);
        }
      }
    }
  } else {
#pragma unroll
    for (int bj = 0; bj < 4; ++bj) {
      int ncol = n0 + wc * 64 + bj * 16 + c;
      float bb = bias[ncol];
#pragma unroll
      for (int ai = 0; ai < 4; ++ai) {
#pragma unroll
        for (int r = 0; r < 4; ++r) {
          int mrow = m0 + wr * 64 + ai * 16 + g * 4 + r;
          out[(size_t)mrow * N + ncol] = acc[ai][bj][r] + bb;
        }
      }
    }
  }
}

// ------------- flash attention: 32x32 MFMA, QBLK=32/wave, 4 blocks/CU -------------
// Conflict-free LDS swizzle slot = col ^ ((row ^ row>>3) & 7); lp in 4 parallel chains.
// Swapped QK^T (S^T = mfma(K,Q)); P in registers via cvt_pk + permlane32_swap;
// streaming no-max softmax (q pre-scaled by CL_).
__global__ __launch_bounds__(256, 4)
void k_attn(const short* __restrict__ q, const short* __restrict__ kk,
            const short* __restrict__ vT, short* __restrict__ ao) {
  __shared__ __align__(16) char smem[32768];  // 2 slots x (K 8K + V 8K)
  constexpr int NT = N_ / 64;  // 32 kv tiles
  int bh = blockIdx.x, qb = blockIdx.y;  // bh fast => same-head blocks on one XCD
  int b = bh >> 4, head = bh & 15;
  int tid = threadIdx.x, w = tid >> 6, lane = tid & 63;
  int half = lane >> 5, qc = lane & 31;
  const size_t ho = (size_t)bh * (N_ * 64);
  const short* Q = q + ho;
  const char* Kc = reinterpret_cast<const char*>(kk + ho);
  const char* Vc = reinterpret_cast<const char*>(vT + ho);
  int q0w = qb * 128 + w * 32;
  // Q B-fragments [ks: k 16-slice]: lane holds q=qc, d=ks*16+half*8+e
  s16x8 qf[4];
#pragma unroll
  for (int ks = 0; ks < 4; ++ks)
    qf[ks] = *reinterpret_cast<const s16x8*>(Q + (size_t)(q0w + qc) * 64 + ks * 16 + half * 8);
  f32x16 ot[2] = {};  // O^T accum [d 32-block]
  float lp0 = 0.f, lp1 = 0.f, lp2 = 0.f, lp3 = 0.f;  // parallel exp-sum chains
  // read-side swizzle: rows r and r+32 differ by ^0x40 in slot bits
  const int rsw0 = ((qc ^ (qc >> 3)) & 7) << 4;  // rows 0..31 (row = qc)
  const int rsw1 = rsw0 ^ 0x40;                  // rows 32..63 (row = 32+qc)
  // staging geometry: LDS dest linear (tid*16); global col-slot = (tid&7) ^ swz8(row)
  const int s_i0 = tid, s_i1 = tid + 256;
  const int s_r0 = s_i0 >> 3, s_r1 = s_i1 >> 3;
  const int s_c0 = (((s_i0 & 7) ^ ((s_r0 ^ (s_r0 >> 3)) & 7)) << 4);
  const int s_c1 = (((s_i1 & 7) ^ ((s_r1 ^ (s_r1 >> 3)) & 7)) << 4);
#define STAGE(T)                                                                       \
  {                                                                                    \
    char* nb = smem + ((T) & 1) * 16384;                                               \
    gload16(Kc + (size_t)((T) * 64 + s_r0) * 128 + s_c0, nb + s_i0 * 16);              \
    gload16(Kc + (size_t)((T) * 64 + s_r1) * 128 + s_c1, nb + s_i1 * 16);              \
    gload16(Vc + (size_t)s_r0 * 4096 + (T) * 128 + s_c0, nb + 8192 + s_i0 * 16);       \
    gload16(Vc + (size_t)s_r1 * 4096 + (T) * 128 + s_c1, nb + 8192 + s_i1 * 16);       \
  }
  STAGE(0);
  __syncthreads();
  for (int tt = 0; tt < NT; ++tt) {
    if (tt + 1 < NT) STAGE(tt + 1);
    const char* kb_ = smem + (tt & 1) * 16384;
    const char* vb_ = kb_ + 8192;
    f32x16 st[2];  // S^T [j kv-blk]
#pragma unroll
    for (int j = 0; j < 2; ++j) {
      const int rs = j ? rsw1 : rsw0;
      s16x8 kfj[4];
#pragma unroll
      for (int ks = 0; ks < 4; ++ks)
        kfj[ks] = *reinterpret_cast<const s16x8*>(kb_ + (j * 32 + qc) * 128 + ((ks * 32 + half * 16) ^ rs));
      f32x16 acc = {};
      __builtin_amdgcn_s_setprio(1);
#pragma unroll
      for (int ks = 0; ks < 4; ++ks)
        acc = __builtin_amdgcn_mfma_f32_32x32x16_bf16(kfj[ks], qf[ks], acc, 0, 0, 0);
      __builtin_amdgcn_s_setprio(0);
      st[j] = acc;
    }
    // streaming softmax (scores pre-scaled by CL_): exp2, 4 parallel partial sums
#pragma unroll
    for (int j = 0; j < 2; ++j)
#pragma unroll
      for (int r = 0; r < 16; ++r) {
        float p = __builtin_amdgcn_exp2f(st[j][r]);
        st[j][r] = p;
        if ((r & 3) == 0) lp0 += p;
        else if ((r & 3) == 1) lp1 += p;
        else if ((r & 3) == 2) lp2 += p;
        else lp3 += p;
      }
    // P -> PV B-fragments in registers: per (j,bb): 4 cvtpk + 2 permlane32_swap
    u32x4 pwv[4];
#pragma unroll
    for (int j = 0; j < 2; ++j)
#pragma unroll
      for (int bb = 0; bb < 2; ++bb)
#pragma unroll
        for (int p = 0; p < 2; ++p) {
          uint32_t Aw = cvtpk(st[j][8 * bb + 2 * p], st[j][8 * bb + 2 * p + 1]);
          uint32_t Bw = cvtpk(st[j][8 * bb + 4 + 2 * p], st[j][8 * bb + 4 + 2 * p + 1]);
          asm volatile("v_permlane32_swap_b32 %0, %1" : "+v"(Aw), "+v"(Bw));
          pwv[j * 2 + bb][p] = Aw;       // word m = p
          pwv[j * 2 + bb][p + 2] = Bw;   // word m = p + 2
        }
    // V^T A-fragments [db: d 32-block][kb4: kv 16-block]: lane holds d=db*32+qc
#pragma unroll
    for (int db = 0; db < 2; ++db) {
      const int rs = db ? rsw1 : rsw0;
      s16x8 vf[4];
#pragma unroll
      for (int kb4 = 0; kb4 < 4; ++kb4)
        vf[kb4] = *reinterpret_cast<const s16x8*>(vb_ + (db * 32 + qc) * 128 + ((kb4 * 32 + half * 16) ^ rs));
      f32x16 acc = ot[db];
      __builtin_amdgcn_s_setprio(1);
#pragma unroll
      for (int kb4 = 0; kb4 < 4; ++kb4)
        acc = __builtin_amdgcn_mfma_f32_32x32x16_bf16(
            vf[kb4], __builtin_bit_cast(s16x8, pwv[kb4]), acc, 0, 0, 0);
      __builtin_amdgcn_s_setprio(0);
      ot[db] = acc;
    }
    __syncthreads();
  }
#undef STAGE
  // l: this lane's half + partner half
  float lp = (lp0 + lp1) + (lp2 + lp3);
  float linv = 1.f / (lp + __shfl_xor(lp, 32, 64));
  // epilogue: per-wave LDS region (all slot reads sealed by final barrier)
  short* Oq = reinterpret_cast<short*>(smem) + w * 2304;  // [32][72]
#pragma unroll
  for (int db = 0; db < 2; ++db)
#pragma unroll
    for (int m = 0; m < 4; ++m) {
      uint2 pk;
      pk.x = cvtpk(ot[db][4 * m] * linv, ot[db][4 * m + 1] * linv);
      pk.y = cvtpk(ot[db][4 * m + 2] * linv, ot[db][4 * m + 3] * linv);
      *reinterpret_cast<uint2*>(Oq + qc * 72 + db * 32 + m * 8 + half * 4) = pk;
    }
  int q2 = lane >> 1, dcol = (lane & 1) * 32;
  size_t ro = (size_t)(b * N_ + q0w + q2) * 1024 + head * 64 + dcol;
#pragma unroll
  for (int ch = 0; ch < 4; ++ch) {
    s16x8 vv = *reinterpret_cast<const s16x8*>(Oq + q2 * 72 + dcol + ch * 8);
    *reinterpret_cast<s16x8*>(ao + ro + ch * 8) = vv;
  }
}

extern "C" void kernel_launch(void* const* d_in, const int* in_sizes, int n_in,
                              void* d_out, int out_size, void* d_ws, size_t ws_size,
                              hipStream_t stream) {
  const float* x = (const float*)d_in[0];
  const float* w_qkv = (const float*)d_in[1];
  const float* w_out = (const float*)d_in[2];
  const float* b_out = (const float*)d_in[3];
  float* out = (float*)d_out;
  char* ws = (char*)d_ws;
  short* xb    = (short*)(ws);                // [8192][1024] bf16 (reused as ao later)
  short* wqkvT = (short*)(ws + 16777216);     // [3072][1024]
  short* woutT = (short*)(ws + 23068672);     // [1024][1024]
  short* qB    = (short*)(ws + 25165824);     // [B][H][N][64] (pre-scaled by CL_)
  short* kB    = (short*)(ws + 41943040);
  short* vtmp  = (short*)(ws + 58720256);
  short* vTT   = (short*)(ws + 75497472);     // [B][H][64][N]
  short* ao    = xb;                          // alias: xb dead after gemm<0>

  k_prep<<<5120, 256, 0, stream>>>(x, xb, w_qkv, wqkvT, w_out, woutT);
  k_gemm<0><<<dim3(64, 24), 256, 0, stream>>>(xb, wqkvT, 8192, 3072, 1024,
                                              qB, kB, vtmp, nullptr, nullptr);
  k_tv<<<dim3(32, 64), 256, 0, stream>>>(vtmp, vTT);
  k_attn<<<dim3(64, 16), 256, 0, stream>>>(qB, kB, vTT, ao);
  k_gemm<1><<<dim3(64, 8), 256, 0, stream>>>(ao, woutT, 8192, 1024, 1024,
                                             nullptr, nullptr, nullptr, b_out, out);
}

// Round 10
// 191.146 us; speedup vs baseline: 1.1162x; 1.0294x over previous
//
#include <hip/hip_runtime.h>
#include <hip/hip_bf16.h>
#include <stdint.h>

typedef __attribute__((ext_vector_type(4))) float f32x4;
typedef __attribute__((ext_vector_type(16))) float f32x16;
typedef __attribute__((ext_vector_type(8))) short s16x8;
typedef __attribute__((ext_vector_type(4))) short s16x4;
typedef __attribute__((ext_vector_type(4))) unsigned int u32x4;

#define DEV static __device__ __forceinline__

constexpr int B_ = 4, H_ = 16, N_ = 2048;
constexpr float CL_ = 0.18033688011112042f;  // dh^-0.5 * log2(e), folded into q

DEV short f2bf(float x) {
  __hip_bfloat16 h = __float2bfloat16(x);
  return *reinterpret_cast<short*>(&h);
}

DEV uint32_t cvtpk(float lo, float hi) {  // packed bf16 (RNE), 1 instr
  uint32_t r;
  asm("v_cvt_pk_bf16_f32 %0, %1, %2" : "=v"(r) : "v"(lo), "v"(hi));
  return r;
}

DEV void gload16(const void* g, void* l) {
  __builtin_amdgcn_global_load_lds((const __attribute__((address_space(1))) void*)g,
                                   (__attribute__((address_space(3))) void*)l, 16, 0, 0);
}

// ---------------- fused prep: x cast + both weight transposes (one launch) ----------
__global__ void k_prep(const float* __restrict__ x, short* __restrict__ xb,
                       const float* __restrict__ wqkv, short* __restrict__ wqkvT,
                       const float* __restrict__ wout, short* __restrict__ woutT) {
  __shared__ short t[64][72];
  int bid = blockIdx.x, tid = threadIdx.x;
  if (bid < 4096) {
    int i = (bid * 256 + tid) * 8;
    const float4* p = reinterpret_cast<const float4*>(x + i);
    float4 a = p[0], b = p[1];
    s16x8 o;
    o[0] = f2bf(a.x); o[1] = f2bf(a.y); o[2] = f2bf(a.z); o[3] = f2bf(a.w);
    o[4] = f2bf(b.x); o[5] = f2bf(b.y); o[6] = f2bf(b.z); o[7] = f2bf(b.w);
    *reinterpret_cast<s16x8*>(xb + i) = o;
    return;
  }
  const float* W;
  short* WT;
  int R = 1024, C, r0, c0;
  if (bid < 4864) {
    int id = bid - 4096;
    W = wqkv; WT = wqkvT; C = 3072;
    c0 = (id % 48) * 64; r0 = (id / 48) * 64;
  } else {
    int id = bid - 4864;
    W = wout; WT = woutT; C = 1024;
    c0 = (id % 16) * 64; r0 = (id / 16) * 64;
  }
  int r = tid >> 2, cp = (tid & 3) * 16;
  const float4* s4 = reinterpret_cast<const float4*>(W + (size_t)(r0 + r) * C + c0 + cp);
  float4 f0 = s4[0], f1 = s4[1], f2 = s4[2], f3 = s4[3];
  short* tr = &t[r][cp];
  tr[0] = f2bf(f0.x); tr[1] = f2bf(f0.y); tr[2]  = f2bf(f0.z); tr[3]  = f2bf(f0.w);
  tr[4] = f2bf(f1.x); tr[5] = f2bf(f1.y); tr[6]  = f2bf(f1.z); tr[7]  = f2bf(f1.w);
  tr[8] = f2bf(f2.x); tr[9] = f2bf(f2.y); tr[10] = f2bf(f2.z); tr[11] = f2bf(f2.w);
  tr[12] = f2bf(f3.x); tr[13] = f2bf(f3.y); tr[14] = f2bf(f3.z); tr[15] = f2bf(f3.w);
  __syncthreads();
  int cc = tid >> 2, rp = (tid & 3) * 16;
  short buf[16];
#pragma unroll
  for (int i = 0; i < 16; ++i) buf[i] = t[rp + i][cc];
  short* dst = WT + (size_t)(c0 + cc) * R + r0 + rp;
  *reinterpret_cast<s16x8*>(dst) = *reinterpret_cast<s16x8*>(buf);
  *reinterpret_cast<s16x8*>(dst + 8) = *reinterpret_cast<s16x8*>(buf + 8);
}

// ------------- GEMM0: xb[8192][1024] x wqkvT[3072][1024] -> q,k ([B][H][N][64]) + vT ----
// 8 waves (2m x 4n, 64x64 each => 128x256 tile), BK=32, 4-slot LDS rotation staged
// 2 tiles ahead, ONE raw s_barrier + counted vmcnt(3) per K-tile (T3/T4: never drain).
// q pre-scaled by CL_; v written TRANSPOSED into vT[B][H][64][N] (kills k_tv).
__global__ __launch_bounds__(512, 2)
void k_gemm0(const short* __restrict__ A, const short* __restrict__ BT,
             short* __restrict__ oq, short* __restrict__ ok, short* __restrict__ ovT) {
  __shared__ __align__(16) char smem[98304];  // 4 slots x (A 8KB + B 16KB)
  constexpr int NT = 32;  // K = 1024 / BK = 32
  const int tid = threadIdx.x;
  const int m0 = blockIdx.x * 128, n0 = blockIdx.y * 256;
  const int lane = tid & 63, w = tid >> 6, g = (lane >> 4) & 3, c = lane & 15;
  const int wm = w & 1, wn = w >> 1;  // 2 x 4 waves, each 64(m) x 64(n)
  f32x4 acc[4][4] = {};
  // staging chunks: A 512 x 16B (1/thread), B 1024 x 16B (2/thread)
  const int ra = tid >> 2, ca = (tid & 3) * 8;
  const int rb1 = ra + 128;
  const short* gA = A + (size_t)(m0 + ra) * 1024 + ca;
  const short* gB0 = BT + (size_t)(n0 + ra) * 1024 + ca;
  const short* gB1 = BT + (size_t)(n0 + rb1) * 1024 + ca;
#define STAGE0(T)                                                   \
  {                                                                 \
    char* nb = smem + ((T) & 3) * 24576;                            \
    gload16(gA + (T) * 32, nb + tid * 16);                          \
    gload16(gB0 + (T) * 32, nb + 8192 + tid * 16);                  \
    gload16(gB1 + (T) * 32, nb + 8192 + (tid + 512) * 16);          \
  }
  STAGE0(0);
  STAGE0(1);
  for (int t = 0; t < NT; ++t) {
    if (t + 1 < NT) {
      asm volatile("s_waitcnt vmcnt(3)" ::: "memory");
    } else {
      asm volatile("s_waitcnt vmcnt(0)" ::: "memory");
    }
    __builtin_amdgcn_s_barrier();
    __builtin_amdgcn_sched_barrier(0);
    if (t + 2 < NT) STAGE0(t + 2);
    const char* sb = smem + (t & 3) * 24576;
    s16x8 af[4], bf[4];
#pragma unroll
    for (int i = 0; i < 4; ++i)
      af[i] = *reinterpret_cast<const s16x8*>(sb + (wm * 64 + i * 16 + c) * 64 + g * 16);
#pragma unroll
    for (int j = 0; j < 4; ++j)
      bf[j] = *reinterpret_cast<const s16x8*>(sb + 8192 + (wn * 64 + j * 16 + c) * 64 + g * 16);
    __builtin_amdgcn_s_setprio(1);
#pragma unroll
    for (int i = 0; i < 4; ++i)
#pragma unroll
      for (int j = 0; j < 4; ++j)
        acc[i][j] = __builtin_amdgcn_mfma_f32_16x16x32_bf16(af[i], bf[j], acc[i][j], 0, 0, 0);
    __builtin_amdgcn_s_setprio(0);
  }
#undef STAGE0
  // epilogue: part 0 -> q (scaled, scatter), 1 -> k (scatter), 2 -> vT (packed 8B rows)
#pragma unroll
  for (int j = 0; j < 4; ++j) {
    int ncol = n0 + wn * 64 + j * 16 + c;
    int part = ncol >> 10;          // uniform per block (256 | 1024)
    int c10 = ncol & 1023;
    int h = c10 >> 6, d = c10 & 63;
    if (part == 2) {
#pragma unroll
      for (int i = 0; i < 4; ++i) {
        int mrow = m0 + wm * 64 + i * 16 + g * 4;  // r=0 row; 4 consecutive
        int b = mrow >> 11, nr = mrow & 2047;
        uint2 pk;
        pk.x = cvtpk(acc[i][j][0], acc[i][j][1]);
        pk.y = cvtpk(acc[i][j][2], acc[i][j][3]);
        *reinterpret_cast<uint2*>(ovT + ((size_t)((b * H_ + h) * 64 + d) * N_ + nr)) = pk;
      }
    } else {
      short* dst0 = (part == 0) ? oq : ok;
      float qs = (part == 0) ? CL_ : 1.0f;
#pragma unroll
      for (int i = 0; i < 4; ++i) {
#pragma unroll
        for (int r = 0; r < 4; ++r) {
          int mrow = m0 + wm * 64 + i * 16 + g * 4 + r;
          int b = mrow >> 11, nr = mrow & 2047;
          dst0[((size_t)((b * H_ + h) * N_ + nr) << 6) + d] = f2bf(acc[i][j][r] * qs);
        }
      }
    }
  }
}

// ------------- GEMM (out-proj): ao[8192][1024] x woutT[1024][1024] + bias -> out fp32 ----
__global__ __launch_bounds__(256, 2)
void k_gemm1(const short* __restrict__ A, const short* __restrict__ BT,
             int M, int N, int K, const float* __restrict__ bias, float* __restrict__ out) {
  __shared__ short As[128 * 32];
  __shared__ short Bs[128 * 32];
  const int tid = threadIdx.x;
  const int m0 = blockIdx.x * 128, n0 = blockIdx.y * 128;
  const int lane = tid & 63, w = tid >> 6, g = lane >> 4, c = lane & 15;
  const int wr = w >> 1, wc = w & 1;
  f32x4 acc[4][4] = {};
  const int trow = tid >> 2, tk = (tid & 3) * 8;
  const short* ga = A + (size_t)(m0 + trow) * K + tk;
  const short* gb = BT + (size_t)(n0 + trow) * K + tk;
  short* la = As + tid * 8;
  short* lb = Bs + tid * 8;
  for (int k0 = 0; k0 < K; k0 += 32) {
    gload16(ga + k0, la);
    gload16(ga + (size_t)64 * K + k0, la + 2048);
    gload16(gb + k0, lb);
    gload16(gb + (size_t)64 * K + k0, lb + 2048);
    __syncthreads();
    s16x8 af[4], bf[4];
#pragma unroll
    for (int i = 0; i < 4; ++i)
      af[i] = *reinterpret_cast<const s16x8*>(As + (wr * 64 + i * 16 + c) * 32 + g * 8);
#pragma unroll
    for (int j = 0; j < 4; ++j)
      bf[j] = *reinterpret_cast<const s16x8*>(Bs + (wc * 64 + j * 16 + c) * 32 + g * 8);
#pragma unroll
    for (int i = 0; i < 4; ++i)
#pragma unroll
      for (int j = 0; j < 4; ++j)
        acc[i][j] = __builtin_amdgcn_mfma_f32_16x16x32_bf16(af[i], bf[j], acc[i][j], 0, 0, 0);
    __syncthreads();
  }
#pragma unroll
  for (int bj = 0; bj < 4; ++bj) {
    int ncol = n0 + wc * 64 + bj * 16 + c;
    float bb = bias[ncol];
#pragma unroll
    for (int ai = 0; ai < 4; ++ai) {
#pragma unroll
      for (int r = 0; r < 4; ++r) {
        int mrow = m0 + wr * 64 + ai * 16 + g * 4 + r;
        out[(size_t)mrow * N + ncol] = acc[ai][bj][r] + bb;
      }
    }
  }
}

// ------------- flash attention: 32x32 MFMA, QBLK=32/wave, 4 blocks/CU (R9) -------------
__global__ __launch_bounds__(256, 4)
void k_attn(const short* __restrict__ q, const short* __restrict__ kk,
            const short* __restrict__ vT, short* __restrict__ ao) {
  __shared__ __align__(16) char smem[32768];  // 2 slots x (K 8K + V 8K)
  constexpr int NT = N_ / 64;  // 32 kv tiles
  int bh = blockIdx.x, qb = blockIdx.y;  // bh fast => same-head blocks on one XCD
  int b = bh >> 4, head = bh & 15;
  int tid = threadIdx.x, w = tid >> 6, lane = tid & 63;
  int half = lane >> 5, qc = lane & 31;
  const size_t ho = (size_t)bh * (N_ * 64);
  const short* Q = q + ho;
  const char* Kc = reinterpret_cast<const char*>(kk + ho);
  const char* Vc = reinterpret_cast<const char*>(vT + ho);
  int q0w = qb * 128 + w * 32;
  s16x8 qf[4];
#pragma unroll
  for (int ks = 0; ks < 4; ++ks)
    qf[ks] = *reinterpret_cast<const s16x8*>(Q + (size_t)(q0w + qc) * 64 + ks * 16 + half * 8);
  f32x16 ot[2] = {};
  float lp0 = 0.f, lp1 = 0.f, lp2 = 0.f, lp3 = 0.f;
  const int rsw0 = ((qc ^ (qc >> 3)) & 7) << 4;
  const int rsw1 = rsw0 ^ 0x40;
  const int s_i0 = tid, s_i1 = tid + 256;
  const int s_r0 = s_i0 >> 3, s_r1 = s_i1 >> 3;
  const int s_c0 = (((s_i0 & 7) ^ ((s_r0 ^ (s_r0 >> 3)) & 7)) << 4);
  const int s_c1 = (((s_i1 & 7) ^ ((s_r1 ^ (s_r1 >> 3)) & 7)) << 4);
#define STAGE(T)                                                                       \
  {                                                                                    \
    char* nb = smem + ((T) & 1) * 16384;                                               \
    gload16(Kc + (size_t)((T) * 64 + s_r0) * 128 + s_c0, nb + s_i0 * 16);              \
    gload16(Kc + (size_t)((T) * 64 + s_r1) * 128 + s_c1, nb + s_i1 * 16);              \
    gload16(Vc + (size_t)s_r0 * 4096 + (T) * 128 + s_c0, nb + 8192 + s_i0 * 16);       \
    gload16(Vc + (size_t)s_r1 * 4096 + (T) * 128 + s_c1, nb + 8192 + s_i1 * 16);       \
  }
  STAGE(0);
  __syncthreads();
  for (int tt = 0; tt < NT; ++tt) {
    if (tt + 1 < NT) STAGE(tt + 1);
    const char* kb_ = smem + (tt & 1) * 16384;
    const char* vb_ = kb_ + 8192;
    f32x16 st[2];
#pragma unroll
    for (int j = 0; j < 2; ++j) {
      const int rs = j ? rsw1 : rsw0;
      s16x8 kfj[4];
#pragma unroll
      for (int ks = 0; ks < 4; ++ks)
        kfj[ks] = *reinterpret_cast<const s16x8*>(kb_ + (j * 32 + qc) * 128 + ((ks * 32 + half * 16) ^ rs));
      f32x16 acc = {};
      __builtin_amdgcn_s_setprio(1);
#pragma unroll
      for (int ks = 0; ks < 4; ++ks)
        acc = __builtin_amdgcn_mfma_f32_32x32x16_bf16(kfj[ks], qf[ks], acc, 0, 0, 0);
      __builtin_amdgcn_s_setprio(0);
      st[j] = acc;
    }
#pragma unroll
    for (int j = 0; j < 2; ++j)
#pragma unroll
      for (int r = 0; r < 16; ++r) {
        float p = __builtin_amdgcn_exp2f(st[j][r]);
        st[j][r] = p;
        if ((r & 3) == 0) lp0 += p;
        else if ((r & 3) == 1) lp1 += p;
        else if ((r & 3) == 2) lp2 += p;
        else lp3 += p;
      }
    u32x4 pwv[4];
#pragma unroll
    for (int j = 0; j < 2; ++j)
#pragma unroll
      for (int bb = 0; bb < 2; ++bb)
#pragma unroll
        for (int p = 0; p < 2; ++p) {
          uint32_t Aw = cvtpk(st[j][8 * bb + 2 * p], st[j][8 * bb + 2 * p + 1]);
          uint32_t Bw = cvtpk(st[j][8 * bb + 4 + 2 * p], st[j][8 * bb + 4 + 2 * p + 1]);
          asm volatile("v_permlane32_swap_b32 %0, %1" : "+v"(Aw), "+v"(Bw));
          pwv[j * 2 + bb][p] = Aw;
          pwv[j * 2 + bb][p + 2] = Bw;
        }
#pragma unroll
    for (int db = 0; db < 2; ++db) {
      const int rs = db ? rsw1 : rsw0;
      s16x8 vf[4];
#pragma unroll
      for (int kb4 = 0; kb4 < 4; ++kb4)
        vf[kb4] = *reinterpret_cast<const s16x8*>(vb_ + (db * 32 + qc) * 128 + ((kb4 * 32 + half * 16) ^ rs));
      f32x16 acc = ot[db];
      __builtin_amdgcn_s_setprio(1);
#pragma unroll
      for (int kb4 = 0; kb4 < 4; ++kb4)
        acc = __builtin_amdgcn_mfma_f32_32x32x16_bf16(
            vf[kb4], __builtin_bit_cast(s16x8, pwv[kb4]), acc, 0, 0, 0);
      __builtin_amdgcn_s_setprio(0);
      ot[db] = acc;
    }
    __syncthreads();
  }
#undef STAGE
  float lp = (lp0 + lp1) + (lp2 + lp3);
  float linv = 1.f / (lp + __shfl_xor(lp, 32, 64));
  short* Oq = reinterpret_cast<short*>(smem) + w * 2304;  // [32][72]
#pragma unroll
  for (int db = 0; db < 2; ++db)
#pragma unroll
    for (int m = 0; m < 4; ++m) {
      uint2 pk;
      pk.x = cvtpk(ot[db][4 * m] * linv, ot[db][4 * m + 1] * linv);
      pk.y = cvtpk(ot[db][4 * m + 2] * linv, ot[db][4 * m + 3] * linv);
      *reinterpret_cast<uint2*>(Oq + qc * 72 + db * 32 + m * 8 + half * 4) = pk;
    }
  int q2 = lane >> 1, dcol = (lane & 1) * 32;
  size_t ro = (size_t)(b * N_ + q0w + q2) * 1024 + head * 64 + dcol;
#pragma unroll
  for (int ch = 0; ch < 4; ++ch) {
    s16x8 vv = *reinterpret_cast<const s16x8*>(Oq + q2 * 72 + dcol + ch * 8);
    *reinterpret_cast<s16x8*>(ao + ro + ch * 8) = vv;
  }
}

extern "C" void kernel_launch(void* const* d_in, const int* in_sizes, int n_in,
                              void* d_out, int out_size, void* d_ws, size_t ws_size,
                              hipStream_t stream) {
  const float* x = (const float*)d_in[0];
  const float* w_qkv = (const float*)d_in[1];
  const float* w_out = (const float*)d_in[2];
  const float* b_out = (const float*)d_in[3];
  float* out = (float*)d_out;
  char* ws = (char*)d_ws;
  short* xb    = (short*)(ws);                // [8192][1024] bf16 (reused as ao later)
  short* wqkvT = (short*)(ws + 16777216);     // [3072][1024]
  short* woutT = (short*)(ws + 23068672);     // [1024][1024]
  short* qB    = (short*)(ws + 25165824);     // [B][H][N][64] (pre-scaled by CL_)
  short* kB    = (short*)(ws + 41943040);
  short* vTT   = (short*)(ws + 75497472);     // [B][H][64][N] (written by gemm0)
  short* ao    = xb;                          // alias: xb dead after gemm0

  k_prep<<<5120, 256, 0, stream>>>(x, xb, w_qkv, wqkvT, w_out, woutT);
  k_gemm0<<<dim3(64, 12), 512, 0, stream>>>(xb, wqkvT, qB, kB, vTT);
  k_attn<<<dim3(64, 16), 256, 0, stream>>>(qB, kB, vTT, ao);
  k_gemm1<<<dim3(64, 8), 256, 0, stream>>>(ao, woutT, 8192, 1024, 1024, b_out, out);
}

// Round 11
// 187.994 us; speedup vs baseline: 1.1350x; 1.0168x over previous
//
#include <hip/hip_runtime.h>
#include <hip/hip_bf16.h>
#include <stdint.h>

typedef __attribute__((ext_vector_type(4))) float f32x4;
typedef __attribute__((ext_vector_type(16))) float f32x16;
typedef __attribute__((ext_vector_type(8))) short s16x8;
typedef __attribute__((ext_vector_type(4))) short s16x4;
typedef __attribute__((ext_vector_type(4))) unsigned int u32x4;

#define DEV static __device__ __forceinline__

constexpr int B_ = 4, H_ = 16, N_ = 2048;
constexpr float CL_ = 0.18033688011112042f;  // dh^-0.5 * log2(e), folded into q

DEV short f2bf(float x) {
  __hip_bfloat16 h = __float2bfloat16(x);
  return *reinterpret_cast<short*>(&h);
}

DEV uint32_t cvtpk(float lo, float hi) {  // packed bf16 (RNE), 1 instr
  uint32_t r;
  asm("v_cvt_pk_bf16_f32 %0, %1, %2" : "=v"(r) : "v"(lo), "v"(hi));
  return r;
}

DEV void gload16(const void* g, void* l) {
  __builtin_amdgcn_global_load_lds((const __attribute__((address_space(1))) void*)g,
                                   (__attribute__((address_space(3))) void*)l, 16, 0, 0);
}

// ---------------- fused prep: x cast + both weight transposes (one launch) ----------
__global__ void k_prep(const float* __restrict__ x, short* __restrict__ xb,
                       const float* __restrict__ wqkv, short* __restrict__ wqkvT,
                       const float* __restrict__ wout, short* __restrict__ woutT) {
  __shared__ short t[64][72];
  int bid = blockIdx.x, tid = threadIdx.x;
  if (bid < 4096) {
    int i = (bid * 256 + tid) * 8;
    const float4* p = reinterpret_cast<const float4*>(x + i);
    float4 a = p[0], b = p[1];
    s16x8 o;
    o[0] = f2bf(a.x); o[1] = f2bf(a.y); o[2] = f2bf(a.z); o[3] = f2bf(a.w);
    o[4] = f2bf(b.x); o[5] = f2bf(b.y); o[6] = f2bf(b.z); o[7] = f2bf(b.w);
    *reinterpret_cast<s16x8*>(xb + i) = o;
    return;
  }
  const float* W;
  short* WT;
  int R = 1024, C, r0, c0;
  if (bid < 4864) {
    int id = bid - 4096;
    W = wqkv; WT = wqkvT; C = 3072;
    c0 = (id % 48) * 64; r0 = (id / 48) * 64;
  } else {
    int id = bid - 4864;
    W = wout; WT = woutT; C = 1024;
    c0 = (id % 16) * 64; r0 = (id / 16) * 64;
  }
  int r = tid >> 2, cp = (tid & 3) * 16;
  const float4* s4 = reinterpret_cast<const float4*>(W + (size_t)(r0 + r) * C + c0 + cp);
  float4 f0 = s4[0], f1 = s4[1], f2 = s4[2], f3 = s4[3];
  short* tr = &t[r][cp];
  tr[0] = f2bf(f0.x); tr[1] = f2bf(f0.y); tr[2]  = f2bf(f0.z); tr[3]  = f2bf(f0.w);
  tr[4] = f2bf(f1.x); tr[5] = f2bf(f1.y); tr[6]  = f2bf(f1.z); tr[7]  = f2bf(f1.w);
  tr[8] = f2bf(f2.x); tr[9] = f2bf(f2.y); tr[10] = f2bf(f2.z); tr[11] = f2bf(f2.w);
  tr[12] = f2bf(f3.x); tr[13] = f2bf(f3.y); tr[14] = f2bf(f3.z); tr[15] = f2bf(f3.w);
  __syncthreads();
  int cc = tid >> 2, rp = (tid & 3) * 16;
  short buf[16];
#pragma unroll
  for (int i = 0; i < 16; ++i) buf[i] = t[rp + i][cc];
  short* dst = WT + (size_t)(c0 + cc) * R + r0 + rp;
  *reinterpret_cast<s16x8*>(dst) = *reinterpret_cast<s16x8*>(buf);
  *reinterpret_cast<s16x8*>(dst + 8) = *reinterpret_cast<s16x8*>(buf + 8);
}

// ------------- GEMM0: xb[8192][1024] x wqkvT[3072][1024] -> q,k ([B][H][N][64]) + vT ----
// 128x128 tile, BK=32, 4 waves, 2-slot LDS (32KB -> 4 blocks/CU), 2-phase pipeline:
// per tile {STAGE(t+1); ds_read(t); MFMA; vmcnt(0); barrier} — one barrier/tile, stage
// lands during compute. q pre-scaled by CL_; v written transposed to vT[B][H][64][N].
__global__ __launch_bounds__(256, 2)
void k_gemm0(const short* __restrict__ A, const short* __restrict__ BT,
             short* __restrict__ oq, short* __restrict__ ok, short* __restrict__ ovT) {
  __shared__ __align__(16) char smem[32768];  // 2 slots x (A 8KB + B 8KB)
  constexpr int K = 1024, NT = 32;
  const int tid = threadIdx.x;
  const int m0 = blockIdx.x * 128, n0 = blockIdx.y * 128;
  const int lane = tid & 63, w = tid >> 6, g = lane >> 4, c = lane & 15;
  const int wr = w >> 1, wc = w & 1;
  f32x4 acc[4][4] = {};
  const int trow = tid >> 2, tk = (tid & 3) * 8;
  const short* ga = A + (size_t)(m0 + trow) * K + tk;
  const short* gb = BT + (size_t)(n0 + trow) * K + tk;
#define STG0(T)                                                    \
  {                                                                \
    char* nb = smem + ((T) & 1) * 16384;                           \
    gload16(ga + (T) * 32, nb + tid * 16);                         \
    gload16(ga + (size_t)64 * K + (T) * 32, nb + 4096 + tid * 16); \
    gload16(gb + (T) * 32, nb + 8192 + tid * 16);                  \
    gload16(gb + (size_t)64 * K + (T) * 32, nb + 12288 + tid * 16);\
  }
  STG0(0);
  asm volatile("s_waitcnt vmcnt(0)" ::: "memory");
  __builtin_amdgcn_s_barrier();
  for (int t = 0; t < NT; ++t) {
    if (t + 1 < NT) STG0(t + 1);
    const char* sb = smem + (t & 1) * 16384;
    s16x8 af[4], bf[4];
#pragma unroll
    for (int i = 0; i < 4; ++i)
      af[i] = *reinterpret_cast<const s16x8*>(sb + (wr * 64 + i * 16 + c) * 64 + g * 16);
#pragma unroll
    for (int j = 0; j < 4; ++j)
      bf[j] = *reinterpret_cast<const s16x8*>(sb + 8192 + (wc * 64 + j * 16 + c) * 64 + g * 16);
    __builtin_amdgcn_s_setprio(1);
#pragma unroll
    for (int i = 0; i < 4; ++i)
#pragma unroll
      for (int j = 0; j < 4; ++j)
        acc[i][j] = __builtin_amdgcn_mfma_f32_16x16x32_bf16(af[i], bf[j], acc[i][j], 0, 0, 0);
    __builtin_amdgcn_s_setprio(0);
    asm volatile("s_waitcnt vmcnt(0)" ::: "memory");
    __builtin_amdgcn_s_barrier();
  }
#undef STG0
  // epilogue: part 0 -> q (scaled), 1 -> k, 2 -> vT (packed 8B rows along n)
#pragma unroll
  for (int bj = 0; bj < 4; ++bj) {
    int ncol = n0 + wc * 64 + bj * 16 + c;
    int part = ncol >> 10;          // uniform per block (tiles never straddle parts)
    int c10 = ncol & 1023;
    int h = c10 >> 6, d = c10 & 63;
    if (part == 2) {
#pragma unroll
      for (int ai = 0; ai < 4; ++ai) {
        int mrow = m0 + wr * 64 + ai * 16 + g * 4;  // 4 consecutive rows
        int b = mrow >> 11, nr = mrow & 2047;
        uint2 pk;
        pk.x = cvtpk(acc[ai][bj][0], acc[ai][bj][1]);
        pk.y = cvtpk(acc[ai][bj][2], acc[ai][bj][3]);
        *reinterpret_cast<uint2*>(ovT + ((size_t)((b * H_ + h) * 64 + d) * N_ + nr)) = pk;
      }
    } else {
      short* dst0 = (part == 0) ? oq : ok;
      float qs = (part == 0) ? CL_ : 1.0f;
#pragma unroll
      for (int ai = 0; ai < 4; ++ai) {
#pragma unroll
        for (int r = 0; r < 4; ++r) {
          int mrow = m0 + wr * 64 + ai * 16 + g * 4 + r;
          int b = mrow >> 11, nr = mrow & 2047;
          dst0[((size_t)((b * H_ + h) * N_ + nr) << 6) + d] = f2bf(acc[ai][bj][r] * qs);
        }
      }
    }
  }
}

// ------------- GEMM1 (out-proj): ao x woutT + bias -> out fp32, same 2-phase loop ----
__global__ __launch_bounds__(256, 2)
void k_gemm1(const short* __restrict__ A, const short* __restrict__ BT,
             int M, int N, int K, const float* __restrict__ bias, float* __restrict__ out) {
  __shared__ __align__(16) char smem[32768];
  const int NT = K / 32;
  const int tid = threadIdx.x;
  const int m0 = blockIdx.x * 128, n0 = blockIdx.y * 128;
  const int lane = tid & 63, w = tid >> 6, g = lane >> 4, c = lane & 15;
  const int wr = w >> 1, wc = w & 1;
  f32x4 acc[4][4] = {};
  const int trow = tid >> 2, tk = (tid & 3) * 8;
  const short* ga = A + (size_t)(m0 + trow) * K + tk;
  const short* gb = BT + (size_t)(n0 + trow) * K + tk;
#define STG1(T)                                                    \
  {                                                                \
    char* nb = smem + ((T) & 1) * 16384;                           \
    gload16(ga + (T) * 32, nb + tid * 16);                         \
    gload16(ga + (size_t)64 * K + (T) * 32, nb + 4096 + tid * 16); \
    gload16(gb + (T) * 32, nb + 8192 + tid * 16);                  \
    gload16(gb + (size_t)64 * K + (T) * 32, nb + 12288 + tid * 16);\
  }
  STG1(0);
  asm volatile("s_waitcnt vmcnt(0)" ::: "memory");
  __builtin_amdgcn_s_barrier();
  for (int t = 0; t < NT; ++t) {
    if (t + 1 < NT) STG1(t + 1);
    const char* sb = smem + (t & 1) * 16384;
    s16x8 af[4], bf[4];
#pragma unroll
    for (int i = 0; i < 4; ++i)
      af[i] = *reinterpret_cast<const s16x8*>(sb + (wr * 64 + i * 16 + c) * 64 + g * 16);
#pragma unroll
    for (int j = 0; j < 4; ++j)
      bf[j] = *reinterpret_cast<const s16x8*>(sb + 8192 + (wc * 64 + j * 16 + c) * 64 + g * 16);
    __builtin_amdgcn_s_setprio(1);
#pragma unroll
    for (int i = 0; i < 4; ++i)
#pragma unroll
      for (int j = 0; j < 4; ++j)
        acc[i][j] = __builtin_amdgcn_mfma_f32_16x16x32_bf16(af[i], bf[j], acc[i][j], 0, 0, 0);
    __builtin_amdgcn_s_setprio(0);
    asm volatile("s_waitcnt vmcnt(0)" ::: "memory");
    __builtin_amdgcn_s_barrier();
  }
#undef STG1
#pragma unroll
  for (int bj = 0; bj < 4; ++bj) {
    int ncol = n0 + wc * 64 + bj * 16 + c;
    float bb = bias[ncol];
#pragma unroll
    for (int ai = 0; ai < 4; ++ai) {
#pragma unroll
      for (int r = 0; r < 4; ++r) {
        int mrow = m0 + wr * 64 + ai * 16 + g * 4 + r;
        out[(size_t)mrow * N + ncol] = acc[ai][bj][r] + bb;
      }
    }
  }
}

// ------------- flash attention: 32x32 MFMA, QBLK=32/wave, 4 blocks/CU (unchanged) ------
__global__ __launch_bounds__(256, 4)
void k_attn(const short* __restrict__ q, const short* __restrict__ kk,
            const short* __restrict__ vT, short* __restrict__ ao) {
  __shared__ __align__(16) char smem[32768];  // 2 slots x (K 8K + V 8K)
  constexpr int NT = N_ / 64;  // 32 kv tiles
  int bh = blockIdx.x, qb = blockIdx.y;  // bh fast => same-head blocks on one XCD
  int b = bh >> 4, head = bh & 15;
  int tid = threadIdx.x, w = tid >> 6, lane = tid & 63;
  int half = lane >> 5, qc = lane & 31;
  const size_t ho = (size_t)bh * (N_ * 64);
  const short* Q = q + ho;
  const char* Kc = reinterpret_cast<const char*>(kk + ho);
  const char* Vc = reinterpret_cast<const char*>(vT + ho);
  int q0w = qb * 128 + w * 32;
  s16x8 qf[4];
#pragma unroll
  for (int ks = 0; ks < 4; ++ks)
    qf[ks] = *reinterpret_cast<const s16x8*>(Q + (size_t)(q0w + qc) * 64 + ks * 16 + half * 8);
  f32x16 ot[2] = {};
  float lp0 = 0.f, lp1 = 0.f, lp2 = 0.f, lp3 = 0.f;
  const int rsw0 = ((qc ^ (qc >> 3)) & 7) << 4;
  const int rsw1 = rsw0 ^ 0x40;
  const int s_i0 = tid, s_i1 = tid + 256;
  const int s_r0 = s_i0 >> 3, s_r1 = s_i1 >> 3;
  const int s_c0 = (((s_i0 & 7) ^ ((s_r0 ^ (s_r0 >> 3)) & 7)) << 4);
  const int s_c1 = (((s_i1 & 7) ^ ((s_r1 ^ (s_r1 >> 3)) & 7)) << 4);
#define STAGE(T)                                                                       \
  {                                                                                    \
    char* nb = smem + ((T) & 1) * 16384;                                               \
    gload16(Kc + (size_t)((T) * 64 + s_r0) * 128 + s_c0, nb + s_i0 * 16);              \
    gload16(Kc + (size_t)((T) * 64 + s_r1) * 128 + s_c1, nb + s_i1 * 16);              \
    gload16(Vc + (size_t)s_r0 * 4096 + (T) * 128 + s_c0, nb + 8192 + s_i0 * 16);       \
    gload16(Vc + (size_t)s_r1 * 4096 + (T) * 128 + s_c1, nb + 8192 + s_i1 * 16);       \
  }
  STAGE(0);
  __syncthreads();
  for (int tt = 0; tt < NT; ++tt) {
    if (tt + 1 < NT) STAGE(tt + 1);
    const char* kb_ = smem + (tt & 1) * 16384;
    const char* vb_ = kb_ + 8192;
    f32x16 st[2];
#pragma unroll
    for (int j = 0; j < 2; ++j) {
      const int rs = j ? rsw1 : rsw0;
      s16x8 kfj[4];
#pragma unroll
      for (int ks = 0; ks < 4; ++ks)
        kfj[ks] = *reinterpret_cast<const s16x8*>(kb_ + (j * 32 + qc) * 128 + ((ks * 32 + half * 16) ^ rs));
      f32x16 acc = {};
      __builtin_amdgcn_s_setprio(1);
#pragma unroll
      for (int ks = 0; ks < 4; ++ks)
        acc = __builtin_amdgcn_mfma_f32_32x32x16_bf16(kfj[ks], qf[ks], acc, 0, 0, 0);
      __builtin_amdgcn_s_setprio(0);
      st[j] = acc;
    }
#pragma unroll
    for (int j = 0; j < 2; ++j)
#pragma unroll
      for (int r = 0; r < 16; ++r) {
        float p = __builtin_amdgcn_exp2f(st[j][r]);
        st[j][r] = p;
        if ((r & 3) == 0) lp0 += p;
        else if ((r & 3) == 1) lp1 += p;
        else if ((r & 3) == 2) lp2 += p;
        else lp3 += p;
      }
    u32x4 pwv[4];
#pragma unroll
    for (int j = 0; j < 2; ++j)
#pragma unroll
      for (int bb = 0; bb < 2; ++bb)
#pragma unroll
        for (int p = 0; p < 2; ++p) {
          uint32_t Aw = cvtpk(st[j][8 * bb + 2 * p], st[j][8 * bb + 2 * p + 1]);
          uint32_t Bw = cvtpk(st[j][8 * bb + 4 + 2 * p], st[j][8 * bb + 4 + 2 * p + 1]);
          asm volatile("v_permlane32_swap_b32 %0, %1" : "+v"(Aw), "+v"(Bw));
          pwv[j * 2 + bb][p] = Aw;
          pwv[j * 2 + bb][p + 2] = Bw;
        }
#pragma unroll
    for (int db = 0; db < 2; ++db) {
      const int rs = db ? rsw1 : rsw0;
      s16x8 vf[4];
#pragma unroll
      for (int kb4 = 0; kb4 < 4; ++kb4)
        vf[kb4] = *reinterpret_cast<const s16x8*>(vb_ + (db * 32 + qc) * 128 + ((kb4 * 32 + half * 16) ^ rs));
      f32x16 acc = ot[db];
      __builtin_amdgcn_s_setprio(1);
#pragma unroll
      for (int kb4 = 0; kb4 < 4; ++kb4)
        acc = __builtin_amdgcn_mfma_f32_32x32x16_bf16(
            vf[kb4], __builtin_bit_cast(s16x8, pwv[kb4]), acc, 0, 0, 0);
      __builtin_amdgcn_s_setprio(0);
      ot[db] = acc;
    }
    __syncthreads();
  }
#undef STAGE
  float lp = (lp0 + lp1) + (lp2 + lp3);
  float linv = 1.f / (lp + __shfl_xor(lp, 32, 64));
  short* Oq = reinterpret_cast<short*>(smem) + w * 2304;  // [32][72]
#pragma unroll
  for (int db = 0; db < 2; ++db)
#pragma unroll
    for (int m = 0; m < 4; ++m) {
      uint2 pk;
      pk.x = cvtpk(ot[db][4 * m] * linv, ot[db][4 * m + 1] * linv);
      pk.y = cvtpk(ot[db][4 * m + 2] * linv, ot[db][4 * m + 3] * linv);
      *reinterpret_cast<uint2*>(Oq + qc * 72 + db * 32 + m * 8 + half * 4) = pk;
    }
  int q2 = lane >> 1, dcol = (lane & 1) * 32;
  size_t ro = (size_t)(b * N_ + q0w + q2) * 1024 + head * 64 + dcol;
#pragma unroll
  for (int ch = 0; ch < 4; ++ch) {
    s16x8 vv = *reinterpret_cast<const s16x8*>(Oq + q2 * 72 + dcol + ch * 8);
    *reinterpret_cast<s16x8*>(ao + ro + ch * 8) = vv;
  }
}

extern "C" void kernel_launch(void* const* d_in, const int* in_sizes, int n_in,
                              void* d_out, int out_size, void* d_ws, size_t ws_size,
                              hipStream_t stream) {
  const float* x = (const float*)d_in[0];
  const float* w_qkv = (const float*)d_in[1];
  const float* w_out = (const float*)d_in[2];
  const float* b_out = (const float*)d_in[3];
  float* out = (float*)d_out;
  char* ws = (char*)d_ws;
  short* xb    = (short*)(ws);                // [8192][1024] bf16 (reused as ao later)
  short* wqkvT = (short*)(ws + 16777216);     // [3072][1024]
  short* woutT = (short*)(ws + 23068672);     // [1024][1024]
  short* qB    = (short*)(ws + 25165824);     // [B][H][N][64] (pre-scaled by CL_)
  short* kB    = (short*)(ws + 41943040);
  short* vTT   = (short*)(ws + 75497472);     // [B][H][64][N] (written by gemm0)
  short* ao    = xb;                          // alias: xb dead after gemm0

  k_prep<<<5120, 256, 0, stream>>>(x, xb, w_qkv, wqkvT, w_out, woutT);
  k_gemm0<<<dim3(64, 24), 256, 0, stream>>>(xb, wqkvT, qB, kB, vTT);
  k_attn<<<dim3(64, 16), 256, 0, stream>>>(qB, kB, vTT, ao);
  k_gemm1<<<dim3(64, 8), 256, 0, stream>>>(ao, woutT, 8192, 1024, 1024, b_out, out);
}